// Round 9
// baseline (564.913 us; speedup 1.0000x reference)
//
#include <hip/hip_runtime.h>
#include <hip/hip_fp16.h>
#include <cstddef>

typedef _Float16 f16;
typedef f16 f16x8 __attribute__((ext_vector_type(8)));
typedef float f32x4 __attribute__((ext_vector_type(4)));

__device__ __forceinline__ unsigned f2mono(float f){
  unsigned u = __float_as_uint(f);
  return (u & 0x80000000u) ? ~u : (u | 0x80000000u);
}
__device__ __forceinline__ float mono2f(unsigned u){
  return (u & 0x80000000u) ? __uint_as_float(u & 0x7fffffffu) : __uint_as_float(~u);
}

// ---------------- weight cast f32 -> f16, 8 x 128x128 ---------------------------
struct WPtrs { const float* w[8]; };
__global__ void k_wcast(WPtrs p, f16* __restrict__ Wh){
  int wi = blockIdx.y;
  const float* W = p.w[wi];
  f16* dst = Wh + (size_t)wi * 16384;
  int i = (blockIdx.x*256 + threadIdx.x) * 8;
  float4 v0 = *(const float4*)(W + i), v1 = *(const float4*)(W + i + 4);
  f16x8 h = {(f16)v0.x,(f16)v0.y,(f16)v0.z,(f16)v0.w,
             (f16)v1.x,(f16)v1.y,(f16)v1.z,(f16)v1.w};
  *(f16x8*)(dst + i) = h;
}

// ---------------- fused two-layer MFMA GEMM: 32 rows x 128 cols ------------------
// B fragments live in REGISTERS per wave; LDS = Al+Ml only (Cf overlays).
template<typename TIN, int MODE>   // MODE 0: write f16 out; MODE 1: +res, fused pooling
__global__ __launch_bounds__(256) void k_gemm2(
    const TIN* __restrict__ in, const f16* __restrict__ W1, const f16* __restrict__ W2,
    const float* __restrict__ b1, const float* __restrict__ b2,
    const __half* __restrict__ resH, __half* __restrict__ outH,
    const int* __restrict__ batch, float* __restrict__ Ps, float* __restrict__ Pss,
    unsigned* __restrict__ Pmx, float* __restrict__ Pcnt, int n)
{
  constexpr int LDW = 130;
  __shared__ __align__(16) char smem[16896];   // Al(8320)+Ml(8320) | Cf(32*132*4)
  f16* Al = (f16*)smem;
  f16* Ml = ((f16*)smem) + 32*LDW;
  float* Cf = (float*)smem;
  __shared__ int ib[32];
  const int tid = threadIdx.x;
  const int r0 = blockIdx.x * 32;
  const int wv = tid >> 6, lane = tid & 63;
  const int l15 = lane & 15, quad = lane >> 4;

  // stage input tile -> Al
#pragma unroll
  for (int i = 0; i < 2; i++){
    int u = tid + 256*i; int row = u >> 4, c8 = (u & 15) * 8;
    int gr = r0 + row;
    f16x8 v = {};
    if (gr < n){
      if constexpr (__is_same(TIN, __half)){
        v = *(const f16x8*)((const f16*)in + (size_t)gr*128 + c8);
      } else {
        const float4* q = (const float4*)((const float*)in + (size_t)gr*128 + c8);
        float4 v0 = q[0], v1 = q[1];
        v = f16x8{(f16)v0.x,(f16)v0.y,(f16)v0.z,(f16)v0.w,
                  (f16)v1.x,(f16)v1.y,(f16)v1.z,(f16)v1.w};
      }
    }
    *(f16x8*)&Al[row*LDW + c8] = v;
  }
  // per-wave B1 fragments straight from global
  f16x8 bf1[2][4];
  {
    const f16* Bp = W1 + (size_t)(wv*32 + l15)*128 + quad*8;
#pragma unroll
    for (int nt = 0; nt < 2; nt++)
#pragma unroll
      for (int kc = 0; kc < 4; kc++)
        bf1[nt][kc] = *(const f16x8*)(Bp + (size_t)nt*16*128 + kc*32);
  }
  __syncthreads();
  // phase 1: 32 rows x 32 cols (cols wv*32..+31)
  f32x4 acc[2][2] = {};
  {
    const f16* Ab = &Al[l15*LDW + quad*8];
#pragma unroll
    for (int kc = 0; kc < 4; kc++){
      f16x8 a0 = *(const f16x8*)(Ab + kc*32);
      f16x8 a1 = *(const f16x8*)(Ab + 16*LDW + kc*32);
#pragma unroll
      for (int nt = 0; nt < 2; nt++){
        acc[0][nt] = __builtin_amdgcn_mfma_f32_16x16x32_f16(a0, bf1[nt][kc], acc[0][nt], 0, 0, 0);
        acc[1][nt] = __builtin_amdgcn_mfma_f32_16x16x32_f16(a1, bf1[nt][kc], acc[1][nt], 0, 0, 0);
      }
    }
  }
  // issue B2 (+resH, batch ids) now: latency rides under Ml writes + barrier
  f16x8 bf2[2][4];
  {
    const f16* Bp = W2 + (size_t)(wv*32 + l15)*128 + quad*8;
#pragma unroll
    for (int nt = 0; nt < 2; nt++)
#pragma unroll
      for (int kc = 0; kc < 4; kc++)
        bf2[nt][kc] = *(const f16x8*)(Bp + (size_t)nt*16*128 + kc*32);
  }
  f16x8 rres[2];
  if constexpr (MODE == 1){
#pragma unroll
    for (int i = 0; i < 2; i++){
      int u = tid + 256*i; int row = u >> 4, c8 = (u & 15) * 8;
      int gr = r0 + row;
      rres[i] = (gr < n) ? *(const f16x8*)((const f16*)resH + (size_t)gr*128 + c8)
                         : f16x8{};
    }
    if (tid < 32){ int gr = r0 + tid; ib[tid] = (gr < n) ? batch[gr] : -1; }
  }
  // mid = relu(acc + b1) -> Ml
#pragma unroll
  for (int nt = 0; nt < 2; nt++){
    int col = wv*32 + nt*16 + l15;
    float bv = b1[col];
#pragma unroll
    for (int rh = 0; rh < 2; rh++)
#pragma unroll
      for (int reg = 0; reg < 4; reg++){
        int row = rh*16 + quad*4 + reg;
        Ml[row*LDW + col] = (f16)fmaxf(acc[rh][nt][reg] + bv, 0.f);
      }
  }
  __syncthreads();            // Ml ready
  // phase 2
  f32x4 acc2[2][2] = {};
  {
    const f16* Ab = &Ml[l15*LDW + quad*8];
#pragma unroll
    for (int kc = 0; kc < 4; kc++){
      f16x8 a0 = *(const f16x8*)(Ab + kc*32);
      f16x8 a1 = *(const f16x8*)(Ab + 16*LDW + kc*32);
#pragma unroll
      for (int nt = 0; nt < 2; nt++){
        acc2[0][nt] = __builtin_amdgcn_mfma_f32_16x16x32_f16(a0, bf2[nt][kc], acc2[0][nt], 0, 0, 0);
        acc2[1][nt] = __builtin_amdgcn_mfma_f32_16x16x32_f16(a1, bf2[nt][kc], acc2[1][nt], 0, 0, 0);
      }
    }
  }
  __syncthreads();            // all Ml reads done; smem becomes Cf
#pragma unroll
  for (int nt = 0; nt < 2; nt++){
    int col = wv*32 + nt*16 + l15;
    float bv = b2[col];
#pragma unroll
    for (int rh = 0; rh < 2; rh++)
#pragma unroll
      for (int reg = 0; reg < 4; reg++){
        int row = rh*16 + quad*4 + reg;
        Cf[row*132 + col] = acc2[rh][nt][reg] + bv;
      }
  }
  __syncthreads();
  if constexpr (MODE == 0){
#pragma unroll
    for (int i = 0; i < 2; i++){
      int u = tid + 256*i;
      int row = u >> 4, c8 = (u & 15) * 8;
      int gr = r0 + row;
      if (gr < n){
        float4 a = *(float4*)&Cf[row*132 + c8];
        float4 b = *(float4*)&Cf[row*132 + c8 + 4];
        f16x8 h = {(f16)a.x,(f16)a.y,(f16)a.z,(f16)a.w,
                   (f16)b.x,(f16)b.y,(f16)b.z,(f16)b.w};
        *(f16x8*)((f16*)outH + (size_t)gr*128 + c8) = h;
      }
    }
  } else {
    // fold residual into Cf in parallel (all 256 threads)
#pragma unroll
    for (int i = 0; i < 2; i++){
      int u = tid + 256*i; int row = u >> 4, c8 = (u & 15) * 8;
      float* p = &Cf[row*132 + c8];
#pragma unroll
      for (int k = 0; k < 8; k++) p[k] += (float)rres[i][k];
    }
    __syncthreads();
    // serial segment pooling: LDS-only
    if (tid < 128){
      int j = tid;
      float sum = 0.f, ssq = 0.f, mx = -1e30f, cnt = 0.f;
      int cur = ib[0];
      auto flush = [&](int b){
        atomicAdd(&Ps[b*128 + j], sum);
        atomicAdd(&Pss[b*128 + j], ssq);
        atomicMax(&Pmx[b*128 + j], f2mono(mx));
        if (j == 0) atomicAdd(&Pcnt[b], cnt);
      };
      for (int r = 0; r < 32; r++){
        int b = ib[r]; if (b < 0) break;
        float v = Cf[r*132 + j];
        if (b != cur){ flush(cur); cur = b; sum = 0.f; ssq = 0.f; mx = -1e30f; cnt = 0.f; }
        sum += v; ssq += v*v; mx = fmaxf(mx, v); cnt += 1.f;
      }
      if (cur >= 0) flush(cur);
    }
  }
}

// ---------------- GAT GEMM (xp = h @ Wg^T) with fused attention-logit prep -------
// 32 rows x 64 cols per block; B slice per wave in registers; LDS = Al only (8.3 KB).
template<int PREP>
__global__ __launch_bounds__(256) void k_gat_gemm(
    const __half* __restrict__ in, const f16* __restrict__ Wm,
    const float* __restrict__ As, const float* __restrict__ Ad,
    float* __restrict__ es, float* __restrict__ ed,
    __half* __restrict__ outH, int n)
{
  constexpr int LDW = 130;
  __shared__ __align__(16) f16 Al[32*LDW];     // St (32*72*2 = 4608B) overlays
  const int tid = threadIdx.x;
  const int ch = blockIdx.x & 1;
  const int r0 = (blockIdx.x >> 1) * 32;
  const int wv = tid >> 6, lane = tid & 63;
  const int l15 = lane & 15, quad = lane >> 4;
  const int rh = wv & 1, cq = wv >> 1;
#pragma unroll
  for (int i = 0; i < 2; i++){
    int u = tid + 256*i; int row = u >> 4, c8 = (u & 15) * 8;
    int gr = r0 + row;
    f16x8 v = {};
    if (gr < n) v = *(const f16x8*)((const f16*)in + (size_t)gr*128 + c8);
    *(f16x8*)&Al[row*LDW + c8] = v;
  }
  // per-wave B fragments from global: rows ch*64 + cq*32 + nt*16 + l15
  f16x8 bf[2][4];
  {
    const f16* Bp = Wm + (size_t)(ch*64 + cq*32 + l15)*128 + quad*8;
#pragma unroll
    for (int nt = 0; nt < 2; nt++)
#pragma unroll
      for (int kc = 0; kc < 4; kc++)
        bf[nt][kc] = *(const f16x8*)(Bp + (size_t)nt*16*128 + kc*32);
  }
  __syncthreads();
  f32x4 acc[2] = {};
  {
    const f16* Ab = &Al[(rh*16 + l15)*LDW + quad*8];
#pragma unroll
    for (int kc = 0; kc < 4; kc++){
      f16x8 a = *(const f16x8*)(Ab + kc*32);
#pragma unroll
      for (int nt = 0; nt < 2; nt++)
        acc[nt] = __builtin_amdgcn_mfma_f32_16x16x32_f16(a, bf[nt][kc], acc[nt], 0, 0, 0);
    }
  }
  // fused logit prep (registers + shuffles only)
  if constexpr (PREP == 1){
#pragma unroll
    for (int nt = 0; nt < 2; nt++){
      int hh = ch*4 + cq*2 + nt;
      float as_ = As[hh*16 + l15], ad_ = Ad[hh*16 + l15];
#pragma unroll
      for (int reg = 0; reg < 4; reg++){
        float se = acc[nt][reg] * as_;
        float sd = acc[nt][reg] * ad_;
#pragma unroll
        for (int off = 1; off < 16; off <<= 1){
          se += __shfl_xor(se, off); sd += __shfl_xor(sd, off);
        }
        int gr = r0 + rh*16 + quad*4 + reg;
        if (l15 == 0 && gr < n){ es[gr*8 + hh] = se; ed[gr*8 + hh] = sd; }
      }
    }
  } else {
    float as_[2], ad_[2];
#pragma unroll
    for (int nt = 0; nt < 2; nt++){
      int col = ch*64 + cq*32 + nt*16 + l15;
      as_[nt] = As[col]; ad_[nt] = Ad[col];
    }
#pragma unroll
    for (int reg = 0; reg < 4; reg++){
      float se = acc[0][reg]*as_[0] + acc[1][reg]*as_[1];
      float sd = acc[0][reg]*ad_[0] + acc[1][reg]*ad_[1];
#pragma unroll
      for (int off = 1; off < 16; off <<= 1){
        se += __shfl_xor(se, off); sd += __shfl_xor(sd, off);
      }
      int gr = r0 + rh*16 + quad*4 + reg;
      if (l15 == 0 && gr < n){ atomicAdd(&es[gr], se); atomicAdd(&ed[gr], sd); }
    }
  }
  // stage xp tile (f16, stride 72), coalesced f16x8 store
  __syncthreads();
  f16* St = Al;
#pragma unroll
  for (int nt = 0; nt < 2; nt++){
    int c2 = cq*32 + nt*16 + l15;
#pragma unroll
    for (int reg = 0; reg < 4; reg++){
      int row = rh*16 + quad*4 + reg;
      St[row*72 + c2] = (f16)acc[nt][reg];
    }
  }
  __syncthreads();
  {
    int row = tid >> 3, c8 = (tid & 7) * 8;
    int gr = r0 + row;
    if (gr < n)
      *(f16x8*)((f16*)outH + (size_t)gr*128 + ch*64 + c8) = *(f16x8*)&St[row*72 + c8];
  }
}

// ---------------- CSR build -----------------------------------------------------
__global__ void k_deg(const int* __restrict__ ei, int* __restrict__ deg, int E, int N){
  int t = blockIdx.x*blockDim.x + threadIdx.x;
  if (t >= E + N) return;
  int d = (t < E) ? ei[E + t] : (t - E);
  atomicAdd(&deg[d], 1);
}
__global__ void k_scan1(const int* __restrict__ deg, int* __restrict__ bsum, int N){
  __shared__ int sd[256];
  int i = blockIdx.x*256 + threadIdx.x;
  sd[threadIdx.x] = (i < N) ? deg[i] : 0;
  __syncthreads();
  for (int s = 128; s > 0; s >>= 1){
    if (threadIdx.x < s) sd[threadIdx.x] += sd[threadIdx.x + s];
    __syncthreads();
  }
  if (threadIdx.x == 0) bsum[blockIdx.x] = sd[0];
}
__global__ void k_scan2(const int* __restrict__ bsum, int* __restrict__ boff, int nb){
  __shared__ int sd[256];
  int t = threadIdx.x;
  int v = (t < nb) ? bsum[t] : 0;
  sd[t] = v;
  __syncthreads();
  for (int s = 1; s < 256; s <<= 1){
    int u = (t >= s) ? sd[t - s] : 0;
    __syncthreads();
    sd[t] += u;
    __syncthreads();
  }
  if (t < nb) boff[t] = sd[t] - v;
}
__global__ void k_scan3(const int* __restrict__ deg, const int* __restrict__ boff,
                        int* __restrict__ rowptr, int N){
  __shared__ int sd[256];
  int tid = threadIdx.x;
  int i = blockIdx.x*256 + tid;
  sd[tid] = (i < N) ? deg[i] : 0;
  __syncthreads();
  for (int s = 1; s < 256; s <<= 1){
    int t = (tid >= s) ? sd[tid - s] : 0;
    __syncthreads();
    sd[tid] += t;
    __syncthreads();
  }
  if (i < N) rowptr[i+1] = boff[blockIdx.x] + sd[tid];
  if (i == 0) rowptr[0] = 0;
}
__global__ void k_fill(const int* __restrict__ ei, const int* __restrict__ rowptr,
                       int* __restrict__ fil, int* __restrict__ csr, int E, int N){
  int t = blockIdx.x*blockDim.x + threadIdx.x;
  if (t >= E + N) return;
  int s, d;
  if (t < E){ s = ei[t]; d = ei[E + t]; } else { s = d = t - E; }
  int pos = rowptr[d] + atomicAdd(&fil[d], 1);
  csr[pos] = s;
}

// ---------------- GAT aggregate: (node, col-half) waves, 16-edge batches ---------
// Wave handles 64 cols of one node. lane = h4*16 + e16: 16 edges x 4 heads per
// batch; lane's own column head (ch*4 + lane>>4) == its logit head h4.
template<int H>
__global__ __launch_bounds__(256) void k_aggregate(
    const __half* __restrict__ xp, const float* __restrict__ es, const float* __restrict__ ed,
    const int* __restrict__ rowptr, const int* __restrict__ csr,
    const float* __restrict__ bg, const __half* __restrict__ resH,
    __half* __restrict__ outH, int N)
{
  int wid = (blockIdx.x*256 + threadIdx.x) >> 6;
  int gw = wid >> 1;
  if (gw >= N) return;
  const int ch = wid & 1;
  const int lane = threadIdx.x & 63;
  const int col = ch*64 + lane;              // f16 column this lane owns
  const int h4 = lane >> 4;                  // logit head block == own col head
  const int e16 = lane & 15;
  const int hh = (H == 8) ? (ch*4 + h4) : 0;
  int beg = rowptr[gw], end = rowptr[gw+1];
  float edv = ed[gw*H + hh];
  float den = 0.f, a = 0.f;
  // prefetch first batch (deg >= 1 always: self-loop)
  int idx = beg + e16; if (idx >= end) idx = end - 1;
  int sE = csr[idx];
  float ev = es[sE*H + hh];
  for (int t = beg; t < end; t += 16){
    int nb = end - t; if (nb > 16) nb = 16;
    int sE_c = sE; float ev_c = ev;
    int tn = t + 16;
    if (tn < end){                           // prefetch next batch
      int idxn = tn + e16; if (idxn >= end) idxn = end - 1;
      sE = csr[idxn];
      ev = es[sE*H + hh];
    }
    float e = ev_c + edv;
    e = e > 0.f ? e : 0.2f*e;
    if (e16 >= nb) e = -1e30f;
    float w = __expf(e);
    float wk[16]; int sk[16];
#pragma unroll
    for (int k = 0; k < 16; k++){
      wk[k] = __shfl(w, (h4 << 4) + k);
      sk[k] = __shfl(sE_c, k);
    }
    float f[16];
#pragma unroll
    for (int k = 0; k < 16; k++)
      f[k] = __half2float(xp[(size_t)sk[k]*128 + col]);
#pragma unroll
    for (int k = 0; k < 16; k++){
      den += wk[k]; a += wk[k]*f[k];
    }
  }
  float o = a / den + bg[col];
  o = o > 0.f ? o : __expf(o) - 1.f;
  if (resH) o += __half2float(resH[(size_t)gw*128 + col]);
  outH[(size_t)gw*128 + col] = __float2half(o);
}

// ---------------- fused poolfin + full classifier head ---------------------------
__global__ void k_poolcls(const float* __restrict__ Ps, const float* __restrict__ Pss,
    const unsigned* __restrict__ Pmx, const float* __restrict__ Pcnt,
    const float* __restrict__ Wc1, const float* __restrict__ bc1,
    const float* __restrict__ Wc2, const float* __restrict__ bc2,
    const float* __restrict__ Wc3, const float* __restrict__ bc3,
    float* __restrict__ out)
{
  __shared__ float gs[384];
  __shared__ float hs[128];
  __shared__ float h2[64];
  int b = blockIdx.x, j = threadIdx.x;
  float cnt = Pcnt[b];
  float c = fmaxf(cnt, 1.f);
  float mean = Ps[b*128 + j] / c;
  float var = (Pss[b*128 + j] - c*mean*mean) / fmaxf(cnt - 1.f, 1.f);
  float sd = (cnt > 1.f) ? sqrtf(fmaxf(var, 0.f)) : 0.f;
  gs[j] = mean; gs[128 + j] = mono2f(Pmx[b*128 + j]); gs[256 + j] = sd;
  __syncthreads();
  float acc = bc1[j];
  const float4* wr = (const float4*)(Wc1 + (size_t)j*384);
  for (int i = 0; i < 96; i++){
    float4 w = wr[i];
    acc += gs[i*4]*w.x + gs[i*4+1]*w.y + gs[i*4+2]*w.z + gs[i*4+3]*w.w;
  }
  hs[j] = fmaxf(acc, 0.f);
  __syncthreads();
  if (j < 64){
    float a2 = bc2[j];
    const float4* w2 = (const float4*)(Wc2 + (size_t)j*128);
    for (int i = 0; i < 32; i++){
      float4 w = w2[i];
      a2 += hs[i*4]*w.x + hs[i*4+1]*w.y + hs[i*4+2]*w.z + hs[i*4+3]*w.w;
    }
    h2[j] = fmaxf(a2, 0.f);
  }
  __syncthreads();
  if (j < 2){
    float a = bc3[j];
    for (int i = 0; i < 64; i++) a += h2[i] * Wc3[j*64 + i];
    out[b*2 + j] = a;
  }
}

// ---------------- launch ---------------------------------------------------------
extern "C" void kernel_launch(void* const* d_in, const int* in_sizes, int n_in,
                              void* d_out, int out_size, void* d_ws, size_t ws_size,
                              hipStream_t stream)
{
  const float* x    = (const float*)d_in[0];
  const int*  ei    = (const int*)d_in[1];
  const int*  batch = (const int*)d_in[2];
  const float* Wi1  = (const float*)d_in[3];  const float* bi1 = (const float*)d_in[4];
  const float* Wi2  = (const float*)d_in[5];  const float* bi2 = (const float*)d_in[6];
  const float* Wg[4]= {(const float*)d_in[7],(const float*)d_in[11],(const float*)d_in[15],(const float*)d_in[19]};
  const float* As[4]= {(const float*)d_in[8],(const float*)d_in[12],(const float*)d_in[16],(const float*)d_in[20]};
  const float* Ad[4]= {(const float*)d_in[9],(const float*)d_in[13],(const float*)d_in[17],(const float*)d_in[21]};
  const float* bg[4]= {(const float*)d_in[10],(const float*)d_in[14],(const float*)d_in[18],(const float*)d_in[22]};
  const float* We1  = (const float*)d_in[23]; const float* be1 = (const float*)d_in[24];
  const float* We2  = (const float*)d_in[25]; const float* be2 = (const float*)d_in[26];
  const float* Wc1  = (const float*)d_in[27]; const float* bc1 = (const float*)d_in[28];
  const float* Wc2  = (const float*)d_in[29]; const float* bc2 = (const float*)d_in[30];
  const float* Wc3  = (const float*)d_in[31]; const float* bc3 = (const float*)d_in[32];
  float* outp = (float*)d_out;

  const int N = in_sizes[2];
  const int E = in_sizes[1] / 2;
  const int Etot = E + N;

  float* base = (float*)d_ws;
  size_t off = 0;
  auto alloc = [&](size_t elems) -> float* {
    float* p = base + off;
    off += (elems + 3) & ~(size_t)3;
    return p;
  };
  __half* Xh  = (__half*)alloc((size_t)N * 64);
  __half* Ah  = (__half*)alloc((size_t)N * 64);
  f16* Wh     = (f16*)alloc(8 * 8192);
  float* es   = alloc((size_t)N * 8);
  float* ed   = alloc((size_t)N * 8);
  float* Ps   = alloc(64 * 128);                 // Ps..ed3 contiguous -> ONE memset
  float* Pss  = alloc(64 * 128);
  unsigned* Pmx = (unsigned*)alloc(64 * 128);
  float* Pcnt = alloc(64);
  int* deg    = (int*)alloc(N);
  int* fil    = (int*)alloc(N);
  float* es3  = alloc(N);
  float* ed3  = alloc(N);
  size_t zend = off;
  int* rowptr = (int*)alloc(N + 1);
  int* bsum   = (int*)alloc(512);
  int* boff   = (int*)alloc(512);
  int* csr    = (int*)alloc(Etot);
  (void)ws_size; (void)n_in; (void)out_size;

  (void)hipMemsetAsync(Ps, 0, (size_t)((base + zend) - Ps) * sizeof(float), stream);

  WPtrs wp;
  wp.w[0]=Wi1; wp.w[1]=Wi2; wp.w[2]=Wg[0]; wp.w[3]=Wg[1]; wp.w[4]=Wg[2]; wp.w[5]=Wg[3]; wp.w[6]=We1; wp.w[7]=We2;
  k_wcast<<<dim3(8, 8), 256, 0, stream>>>(wp, Wh);

  const int g2 = (N + 31) / 32;
  const int gtiles = 2 * g2;
  const int gagg = (2*N + 3) / 4;
  // input_proj: Ah = half(relu(x@Wi1^T+bi1)@Wi2^T+bi2)
  k_gemm2<float, 0><<<g2, 256, 0, stream>>>(x, Wh + 0*16384, Wh + 1*16384, bi1, bi2,
                                            nullptr, Ah, nullptr, nullptr, nullptr, nullptr, nullptr, N);

  const int nb = (N + 255) / 256;
  k_deg  <<<(Etot + 255) / 256, 256, 0, stream>>>(ei, deg, E, N);
  k_scan1<<<nb, 256, 0, stream>>>(deg, bsum, N);
  k_scan2<<<1, 256, 0, stream>>>(bsum, boff, nb);
  k_scan3<<<nb, 256, 0, stream>>>(deg, boff, rowptr, N);
  k_fill <<<(Etot + 255) / 256, 256, 0, stream>>>(ei, rowptr, fil, csr, E, N);

  for (int l = 0; l < 4; l++){
    if (l < 3){
      k_gat_gemm<1><<<gtiles, 256, 0, stream>>>(Ah, Wh + (size_t)(2+l)*16384, As[l], Ad[l],
                                                es, ed, Xh, N);
      k_aggregate<8><<<gagg, 256, 0, stream>>>(Xh, es, ed, rowptr, csr, bg[l],
                                               l > 0 ? Ah : nullptr, Ah, N);
    } else {
      k_gat_gemm<2><<<gtiles, 256, 0, stream>>>(Ah, Wh + 5*16384, As[3], Ad[3],
                                                es3, ed3, Xh, N);
      k_aggregate<1><<<gagg, 256, 0, stream>>>(Xh, es3, ed3, rowptr, csr, bg[3],
                                               Ah, Ah, N);
    }
  }

  // enh = Ah + (relu(Ah@We1^T+be1)@We2^T + be2) -> fused pooling atomics only
  k_gemm2<__half, 1><<<g2, 256, 0, stream>>>(Ah, Wh + 6*16384, Wh + 7*16384, be1, be2,
                                             Ah, nullptr, batch, Ps, Pss, Pmx, Pcnt, N);

  k_poolcls<<<64, 128, 0, stream>>>(Ps, Pss, Pmx, Pcnt, Wc1, bc1, Wc2, bc2, Wc3, bc3, outp);
}

// Round 10
// 483.371 us; speedup vs baseline: 1.1687x; 1.1687x over previous
//
#include <hip/hip_runtime.h>
#include <hip/hip_fp16.h>
#include <cstddef>

typedef _Float16 f16;
typedef f16 f16x8 __attribute__((ext_vector_type(8)));
typedef float f32x4 __attribute__((ext_vector_type(4)));

__device__ __forceinline__ unsigned f2mono(float f){
  unsigned u = __float_as_uint(f);
  return (u & 0x80000000u) ? ~u : (u | 0x80000000u);
}
__device__ __forceinline__ float mono2f(unsigned u){
  return (u & 0x80000000u) ? __uint_as_float(u & 0x7fffffffu) : __uint_as_float(~u);
}

// ---------------- weight cast f32 -> f16, 8 x 128x128 ---------------------------
struct WPtrs { const float* w[8]; };
__global__ void k_wcast(WPtrs p, f16* __restrict__ Wh){
  int wi = blockIdx.y;
  const float* W = p.w[wi];
  f16* dst = Wh + (size_t)wi * 16384;
  int i = (blockIdx.x*256 + threadIdx.x) * 8;
  float4 v0 = *(const float4*)(W + i), v1 = *(const float4*)(W + i + 4);
  f16x8 h = {(f16)v0.x,(f16)v0.y,(f16)v0.z,(f16)v0.w,
             (f16)v1.x,(f16)v1.y,(f16)v1.z,(f16)v1.w};
  *(f16x8*)(dst + i) = h;
}

// ---------------- fused two-layer MFMA GEMM: 32 rows x 128 cols ------------------
// B fragments live in REGISTERS per wave; LDS = Al+Ml only (Cf overlays).
template<typename TIN, int MODE>   // MODE 0: write f16 out; MODE 1: +res, fused pooling
__global__ __launch_bounds__(256) void k_gemm2(
    const TIN* __restrict__ in, const f16* __restrict__ W1, const f16* __restrict__ W2,
    const float* __restrict__ b1, const float* __restrict__ b2,
    const __half* __restrict__ resH, __half* __restrict__ outH,
    const int* __restrict__ batch, float* __restrict__ Ps, float* __restrict__ Pss,
    unsigned* __restrict__ Pmx, float* __restrict__ Pcnt, int n)
{
  constexpr int LDW = 130;
  __shared__ __align__(16) char smem[16896];   // Al(8320)+Ml(8320) | Cf(32*132*4)
  f16* Al = (f16*)smem;
  f16* Ml = ((f16*)smem) + 32*LDW;
  float* Cf = (float*)smem;
  __shared__ int ib[32];
  const int tid = threadIdx.x;
  const int r0 = blockIdx.x * 32;
  const int wv = tid >> 6, lane = tid & 63;
  const int l15 = lane & 15, quad = lane >> 4;

  // stage input tile -> Al
#pragma unroll
  for (int i = 0; i < 2; i++){
    int u = tid + 256*i; int row = u >> 4, c8 = (u & 15) * 8;
    int gr = r0 + row;
    f16x8 v = {};
    if (gr < n){
      if constexpr (__is_same(TIN, __half)){
        v = *(const f16x8*)((const f16*)in + (size_t)gr*128 + c8);
      } else {
        const float4* q = (const float4*)((const float*)in + (size_t)gr*128 + c8);
        float4 v0 = q[0], v1 = q[1];
        v = f16x8{(f16)v0.x,(f16)v0.y,(f16)v0.z,(f16)v0.w,
                  (f16)v1.x,(f16)v1.y,(f16)v1.z,(f16)v1.w};
      }
    }
    *(f16x8*)&Al[row*LDW + c8] = v;
  }
  // per-wave B1 fragments straight from global
  f16x8 bf1[2][4];
  {
    const f16* Bp = W1 + (size_t)(wv*32 + l15)*128 + quad*8;
#pragma unroll
    for (int nt = 0; nt < 2; nt++)
#pragma unroll
      for (int kc = 0; kc < 4; kc++)
        bf1[nt][kc] = *(const f16x8*)(Bp + (size_t)nt*16*128 + kc*32);
  }
  __syncthreads();
  // phase 1: 32 rows x 32 cols (cols wv*32..+31)
  f32x4 acc[2][2] = {};
  {
    const f16* Ab = &Al[l15*LDW + quad*8];
#pragma unroll
    for (int kc = 0; kc < 4; kc++){
      f16x8 a0 = *(const f16x8*)(Ab + kc*32);
      f16x8 a1 = *(const f16x8*)(Ab + 16*LDW + kc*32);
#pragma unroll
      for (int nt = 0; nt < 2; nt++){
        acc[0][nt] = __builtin_amdgcn_mfma_f32_16x16x32_f16(a0, bf1[nt][kc], acc[0][nt], 0, 0, 0);
        acc[1][nt] = __builtin_amdgcn_mfma_f32_16x16x32_f16(a1, bf1[nt][kc], acc[1][nt], 0, 0, 0);
      }
    }
  }
  // issue B2 (+resH, batch ids) now: latency rides under Ml writes + barrier
  f16x8 bf2[2][4];
  {
    const f16* Bp = W2 + (size_t)(wv*32 + l15)*128 + quad*8;
#pragma unroll
    for (int nt = 0; nt < 2; nt++)
#pragma unroll
      for (int kc = 0; kc < 4; kc++)
        bf2[nt][kc] = *(const f16x8*)(Bp + (size_t)nt*16*128 + kc*32);
  }
  f16x8 rres[2];
  if constexpr (MODE == 1){
#pragma unroll
    for (int i = 0; i < 2; i++){
      int u = tid + 256*i; int row = u >> 4, c8 = (u & 15) * 8;
      int gr = r0 + row;
      rres[i] = (gr < n) ? *(const f16x8*)((const f16*)resH + (size_t)gr*128 + c8)
                         : f16x8{};
    }
    if (tid < 32){ int gr = r0 + tid; ib[tid] = (gr < n) ? batch[gr] : -1; }
  }
  // mid = relu(acc + b1) -> Ml
#pragma unroll
  for (int nt = 0; nt < 2; nt++){
    int col = wv*32 + nt*16 + l15;
    float bv = b1[col];
#pragma unroll
    for (int rh = 0; rh < 2; rh++)
#pragma unroll
      for (int reg = 0; reg < 4; reg++){
        int row = rh*16 + quad*4 + reg;
        Ml[row*LDW + col] = (f16)fmaxf(acc[rh][nt][reg] + bv, 0.f);
      }
  }
  __syncthreads();            // Ml ready
  // phase 2
  f32x4 acc2[2][2] = {};
  {
    const f16* Ab = &Ml[l15*LDW + quad*8];
#pragma unroll
    for (int kc = 0; kc < 4; kc++){
      f16x8 a0 = *(const f16x8*)(Ab + kc*32);
      f16x8 a1 = *(const f16x8*)(Ab + 16*LDW + kc*32);
#pragma unroll
      for (int nt = 0; nt < 2; nt++){
        acc2[0][nt] = __builtin_amdgcn_mfma_f32_16x16x32_f16(a0, bf2[nt][kc], acc2[0][nt], 0, 0, 0);
        acc2[1][nt] = __builtin_amdgcn_mfma_f32_16x16x32_f16(a1, bf2[nt][kc], acc2[1][nt], 0, 0, 0);
      }
    }
  }
  __syncthreads();            // all Ml reads done; smem becomes Cf
#pragma unroll
  for (int nt = 0; nt < 2; nt++){
    int col = wv*32 + nt*16 + l15;
    float bv = b2[col];
#pragma unroll
    for (int rh = 0; rh < 2; rh++)
#pragma unroll
      for (int reg = 0; reg < 4; reg++){
        int row = rh*16 + quad*4 + reg;
        Cf[row*132 + col] = acc2[rh][nt][reg] + bv;
      }
  }
  __syncthreads();
  if constexpr (MODE == 0){
#pragma unroll
    for (int i = 0; i < 2; i++){
      int u = tid + 256*i;
      int row = u >> 4, c8 = (u & 15) * 8;
      int gr = r0 + row;
      if (gr < n){
        float4 a = *(float4*)&Cf[row*132 + c8];
        float4 b = *(float4*)&Cf[row*132 + c8 + 4];
        f16x8 h = {(f16)a.x,(f16)a.y,(f16)a.z,(f16)a.w,
                   (f16)b.x,(f16)b.y,(f16)b.z,(f16)b.w};
        *(f16x8*)((f16*)outH + (size_t)gr*128 + c8) = h;
      }
    }
  } else {
    // fold residual into Cf in parallel (all 256 threads)
#pragma unroll
    for (int i = 0; i < 2; i++){
      int u = tid + 256*i; int row = u >> 4, c8 = (u & 15) * 8;
      float* p = &Cf[row*132 + c8];
#pragma unroll
      for (int k = 0; k < 8; k++) p[k] += (float)rres[i][k];
    }
    __syncthreads();
    // serial segment pooling: LDS-only
    if (tid < 128){
      int j = tid;
      float sum = 0.f, ssq = 0.f, mx = -1e30f, cnt = 0.f;
      int cur = ib[0];
      auto flush = [&](int b){
        atomicAdd(&Ps[b*128 + j], sum);
        atomicAdd(&Pss[b*128 + j], ssq);
        atomicMax(&Pmx[b*128 + j], f2mono(mx));
        if (j == 0) atomicAdd(&Pcnt[b], cnt);
      };
      for (int r = 0; r < 32; r++){
        int b = ib[r]; if (b < 0) break;
        float v = Cf[r*132 + j];
        if (b != cur){ flush(cur); cur = b; sum = 0.f; ssq = 0.f; mx = -1e30f; cnt = 0.f; }
        sum += v; ssq += v*v; mx = fmaxf(mx, v); cnt += 1.f;
      }
      if (cur >= 0) flush(cur);
    }
  }
}

// ---------------- GAT GEMM (xp = h @ Wg^T) with fused attention-logit prep -------
// 32 rows x 64 cols per block; B slice per wave in registers; LDS = Al only (8.3 KB).
template<int PREP>
__global__ __launch_bounds__(256) void k_gat_gemm(
    const __half* __restrict__ in, const f16* __restrict__ Wm,
    const float* __restrict__ As, const float* __restrict__ Ad,
    float* __restrict__ es, float* __restrict__ ed,
    __half* __restrict__ outH, int n)
{
  constexpr int LDW = 130;
  __shared__ __align__(16) f16 Al[32*LDW];     // St (32*72*2 = 4608B) overlays
  const int tid = threadIdx.x;
  const int ch = blockIdx.x & 1;
  const int r0 = (blockIdx.x >> 1) * 32;
  const int wv = tid >> 6, lane = tid & 63;
  const int l15 = lane & 15, quad = lane >> 4;
  const int rh = wv & 1, cq = wv >> 1;
#pragma unroll
  for (int i = 0; i < 2; i++){
    int u = tid + 256*i; int row = u >> 4, c8 = (u & 15) * 8;
    int gr = r0 + row;
    f16x8 v = {};
    if (gr < n) v = *(const f16x8*)((const f16*)in + (size_t)gr*128 + c8);
    *(f16x8*)&Al[row*LDW + c8] = v;
  }
  // per-wave B fragments from global: rows ch*64 + cq*32 + nt*16 + l15
  f16x8 bf[2][4];
  {
    const f16* Bp = Wm + (size_t)(ch*64 + cq*32 + l15)*128 + quad*8;
#pragma unroll
    for (int nt = 0; nt < 2; nt++)
#pragma unroll
      for (int kc = 0; kc < 4; kc++)
        bf[nt][kc] = *(const f16x8*)(Bp + (size_t)nt*16*128 + kc*32);
  }
  __syncthreads();
  f32x4 acc[2] = {};
  {
    const f16* Ab = &Al[(rh*16 + l15)*LDW + quad*8];
#pragma unroll
    for (int kc = 0; kc < 4; kc++){
      f16x8 a = *(const f16x8*)(Ab + kc*32);
#pragma unroll
      for (int nt = 0; nt < 2; nt++)
        acc[nt] = __builtin_amdgcn_mfma_f32_16x16x32_f16(a, bf[nt][kc], acc[nt], 0, 0, 0);
    }
  }
  // fused logit prep (registers + shuffles only)
  if constexpr (PREP == 1){
#pragma unroll
    for (int nt = 0; nt < 2; nt++){
      int hh = ch*4 + cq*2 + nt;
      float as_ = As[hh*16 + l15], ad_ = Ad[hh*16 + l15];
#pragma unroll
      for (int reg = 0; reg < 4; reg++){
        float se = acc[nt][reg] * as_;
        float sd = acc[nt][reg] * ad_;
#pragma unroll
        for (int off = 1; off < 16; off <<= 1){
          se += __shfl_xor(se, off); sd += __shfl_xor(sd, off);
        }
        int gr = r0 + rh*16 + quad*4 + reg;
        if (l15 == 0 && gr < n){ es[gr*8 + hh] = se; ed[gr*8 + hh] = sd; }
      }
    }
  } else {
    float as_[2], ad_[2];
#pragma unroll
    for (int nt = 0; nt < 2; nt++){
      int col = ch*64 + cq*32 + nt*16 + l15;
      as_[nt] = As[col]; ad_[nt] = Ad[col];
    }
#pragma unroll
    for (int reg = 0; reg < 4; reg++){
      float se = acc[0][reg]*as_[0] + acc[1][reg]*as_[1];
      float sd = acc[0][reg]*ad_[0] + acc[1][reg]*ad_[1];
#pragma unroll
      for (int off = 1; off < 16; off <<= 1){
        se += __shfl_xor(se, off); sd += __shfl_xor(sd, off);
      }
      int gr = r0 + rh*16 + quad*4 + reg;
      if (l15 == 0 && gr < n){ atomicAdd(&es[gr], se); atomicAdd(&ed[gr], sd); }
    }
  }
  // stage xp tile (f16, stride 72), coalesced f16x8 store
  __syncthreads();
  f16* St = Al;
#pragma unroll
  for (int nt = 0; nt < 2; nt++){
    int c2 = cq*32 + nt*16 + l15;
#pragma unroll
    for (int reg = 0; reg < 4; reg++){
      int row = rh*16 + quad*4 + reg;
      St[row*72 + c2] = (f16)acc[nt][reg];
    }
  }
  __syncthreads();
  {
    int row = tid >> 3, c8 = (tid & 7) * 8;
    int gr = r0 + row;
    if (gr < n)
      *(f16x8*)((f16*)outH + (size_t)gr*128 + ch*64 + c8) = *(f16x8*)&St[row*72 + c8];
  }
}

// ---------------- CSR build -----------------------------------------------------
__global__ void k_deg(const int* __restrict__ ei, int* __restrict__ deg, int E, int N){
  int t = blockIdx.x*blockDim.x + threadIdx.x;
  if (t >= E + N) return;
  int d = (t < E) ? ei[E + t] : (t - E);
  atomicAdd(&deg[d], 1);
}
__global__ void k_scan1(const int* __restrict__ deg, int* __restrict__ bsum, int N){
  __shared__ int sd[256];
  int i = blockIdx.x*256 + threadIdx.x;
  sd[threadIdx.x] = (i < N) ? deg[i] : 0;
  __syncthreads();
  for (int s = 128; s > 0; s >>= 1){
    if (threadIdx.x < s) sd[threadIdx.x] += sd[threadIdx.x + s];
    __syncthreads();
  }
  if (threadIdx.x == 0) bsum[blockIdx.x] = sd[0];
}
__global__ void k_scan2(const int* __restrict__ bsum, int* __restrict__ boff, int nb){
  __shared__ int sd[256];
  int t = threadIdx.x;
  int v = (t < nb) ? bsum[t] : 0;
  sd[t] = v;
  __syncthreads();
  for (int s = 1; s < 256; s <<= 1){
    int u = (t >= s) ? sd[t - s] : 0;
    __syncthreads();
    sd[t] += u;
    __syncthreads();
  }
  if (t < nb) boff[t] = sd[t] - v;
}
__global__ void k_scan3(const int* __restrict__ deg, const int* __restrict__ boff,
                        int* __restrict__ rowptr, int N){
  __shared__ int sd[256];
  int tid = threadIdx.x;
  int i = blockIdx.x*256 + tid;
  sd[tid] = (i < N) ? deg[i] : 0;
  __syncthreads();
  for (int s = 1; s < 256; s <<= 1){
    int t = (tid >= s) ? sd[tid - s] : 0;
    __syncthreads();
    sd[tid] += t;
    __syncthreads();
  }
  if (i < N) rowptr[i+1] = boff[blockIdx.x] + sd[tid];
  if (i == 0) rowptr[0] = 0;
}
__global__ void k_fill(const int* __restrict__ ei, const int* __restrict__ rowptr,
                       int* __restrict__ fil, int* __restrict__ csr, int E, int N){
  int t = blockIdx.x*blockDim.x + threadIdx.x;
  if (t >= E + N) return;
  int s, d;
  if (t < E){ s = ei[t]; d = ei[E + t]; } else { s = d = t - E; }
  int pos = rowptr[d] + atomicAdd(&fil[d], 1);
  csr[pos] = s;
}

// ---------------- GAT aggregate (R7 form): 8-edge batches, half2 gathers ---------
// One wave per dst node; lane owns col pair j0=lane*2; 32-bit gather indexing.
template<int H, int D>
__global__ __launch_bounds__(256) void k_aggregate(
    const __half* __restrict__ xp, const float* __restrict__ es, const float* __restrict__ ed,
    const int* __restrict__ rowptr, const int* __restrict__ csr,
    const float* __restrict__ bg, const __half* __restrict__ resH,
    __half* __restrict__ outH, int N)
{
  int gw = (blockIdx.x*256 + threadIdx.x) >> 6;
  if (gw >= N) return;
  const int lane = threadIdx.x & 63;
  const int j0 = lane*2;
  const int h0 = (H == 8) ? (lane >> 3) : 0;
  const int k8 = lane & 7;
  const __half2* __restrict__ xp2 = (const __half2*)xp;
  int beg = rowptr[gw], end = rowptr[gw+1];
  float edv = ed[gw*H + h0];
  float den = 0.f, a0 = 0.f, a1 = 0.f;
  // prefetch first batch (deg >= 1 always: self-loop)
  int idx = beg + k8; if (idx >= end) idx = end - 1;
  int sE = csr[idx];
  float ev = es[(unsigned)sE*H + h0];
  for (int t = beg; t < end; t += 8){
    int nb = end - t; if (nb > 8) nb = 8;
    int sE_c = sE; float ev_c = ev;
    int tn = t + 8;
    if (tn < end){                       // prefetch next batch
      int idxn = tn + k8; if (idxn >= end) idxn = end - 1;
      sE = csr[idxn];
      ev = es[(unsigned)sE*H + h0];
    }
    float e = ev_c + edv;
    e = e > 0.f ? e : 0.2f*e;
    if (k8 >= nb) e = -1e30f;
    float w = __expf(e);
    float wk[8]; int sk[8];
#pragma unroll
    for (int k = 0; k < 8; k++){
      wk[k] = __shfl(w, (h0 << 3) + k);
      sk[k] = __shfl(sE_c, k);
    }
    float2 f[8];
#pragma unroll
    for (int k = 0; k < 8; k++)
      f[k] = __half22float2(xp2[(unsigned)sk[k]*64u + (unsigned)lane]);
#pragma unroll
    for (int k = 0; k < 8; k++){
      den += wk[k]; a0 += wk[k]*f[k].x; a1 += wk[k]*f[k].y;
    }
  }
  float inv = 1.f / den;
  float o0 = a0*inv + bg[j0];
  float o1 = a1*inv + bg[j0+1];
  o0 = o0 > 0.f ? o0 : __expf(o0) - 1.f;
  o1 = o1 > 0.f ? o1 : __expf(o1) - 1.f;
  if (resH){
    float2 r = __half22float2(*(const __half2*)(resH + (size_t)gw*128 + j0));
    o0 += r.x; o1 += r.y;
  }
  *(__half2*)(outH + (size_t)gw*128 + j0) = __floats2half2_rn(o0, o1);
}

// ---------------- fused poolfin + full classifier head ---------------------------
__global__ void k_poolcls(const float* __restrict__ Ps, const float* __restrict__ Pss,
    const unsigned* __restrict__ Pmx, const float* __restrict__ Pcnt,
    const float* __restrict__ Wc1, const float* __restrict__ bc1,
    const float* __restrict__ Wc2, const float* __restrict__ bc2,
    const float* __restrict__ Wc3, const float* __restrict__ bc3,
    float* __restrict__ out)
{
  __shared__ float gs[384];
  __shared__ float hs[128];
  __shared__ float h2[64];
  int b = blockIdx.x, j = threadIdx.x;
  float cnt = Pcnt[b];
  float c = fmaxf(cnt, 1.f);
  float mean = Ps[b*128 + j] / c;
  float var = (Pss[b*128 + j] - c*mean*mean) / fmaxf(cnt - 1.f, 1.f);
  float sd = (cnt > 1.f) ? sqrtf(fmaxf(var, 0.f)) : 0.f;
  gs[j] = mean; gs[128 + j] = mono2f(Pmx[b*128 + j]); gs[256 + j] = sd;
  __syncthreads();
  float acc = bc1[j];
  const float4* wr = (const float4*)(Wc1 + (size_t)j*384);
  for (int i = 0; i < 96; i++){
    float4 w = wr[i];
    acc += gs[i*4]*w.x + gs[i*4+1]*w.y + gs[i*4+2]*w.z + gs[i*4+3]*w.w;
  }
  hs[j] = fmaxf(acc, 0.f);
  __syncthreads();
  if (j < 64){
    float a2 = bc2[j];
    const float4* w2 = (const float4*)(Wc2 + (size_t)j*128);
    for (int i = 0; i < 32; i++){
      float4 w = w2[i];
      a2 += hs[i*4]*w.x + hs[i*4+1]*w.y + hs[i*4+2]*w.z + hs[i*4+3]*w.w;
    }
    h2[j] = fmaxf(a2, 0.f);
  }
  __syncthreads();
  if (j < 2){
    float a = bc3[j];
    for (int i = 0; i < 64; i++) a += h2[i] * Wc3[j*64 + i];
    out[b*2 + j] = a;
  }
}

// ---------------- launch ---------------------------------------------------------
extern "C" void kernel_launch(void* const* d_in, const int* in_sizes, int n_in,
                              void* d_out, int out_size, void* d_ws, size_t ws_size,
                              hipStream_t stream)
{
  const float* x    = (const float*)d_in[0];
  const int*  ei    = (const int*)d_in[1];
  const int*  batch = (const int*)d_in[2];
  const float* Wi1  = (const float*)d_in[3];  const float* bi1 = (const float*)d_in[4];
  const float* Wi2  = (const float*)d_in[5];  const float* bi2 = (const float*)d_in[6];
  const float* Wg[4]= {(const float*)d_in[7],(const float*)d_in[11],(const float*)d_in[15],(const float*)d_in[19]};
  const float* As[4]= {(const float*)d_in[8],(const float*)d_in[12],(const float*)d_in[16],(const float*)d_in[20]};
  const float* Ad[4]= {(const float*)d_in[9],(const float*)d_in[13],(const float*)d_in[17],(const float*)d_in[21]};
  const float* bg[4]= {(const float*)d_in[10],(const float*)d_in[14],(const float*)d_in[18],(const float*)d_in[22]};
  const float* We1  = (const float*)d_in[23]; const float* be1 = (const float*)d_in[24];
  const float* We2  = (const float*)d_in[25]; const float* be2 = (const float*)d_in[26];
  const float* Wc1  = (const float*)d_in[27]; const float* bc1 = (const float*)d_in[28];
  const float* Wc2  = (const float*)d_in[29]; const float* bc2 = (const float*)d_in[30];
  const float* Wc3  = (const float*)d_in[31]; const float* bc3 = (const float*)d_in[32];
  float* outp = (float*)d_out;

  const int N = in_sizes[2];
  const int E = in_sizes[1] / 2;
  const int Etot = E + N;

  float* base = (float*)d_ws;
  size_t off = 0;
  auto alloc = [&](size_t elems) -> float* {
    float* p = base + off;
    off += (elems + 3) & ~(size_t)3;
    return p;
  };
  __half* Xh  = (__half*)alloc((size_t)N * 64);
  __half* Ah  = (__half*)alloc((size_t)N * 64);
  f16* Wh     = (f16*)alloc(8 * 8192);
  float* es   = alloc((size_t)N * 8);
  float* ed   = alloc((size_t)N * 8);
  float* Ps   = alloc(64 * 128);                 // Ps..ed3 contiguous -> ONE memset
  float* Pss  = alloc(64 * 128);
  unsigned* Pmx = (unsigned*)alloc(64 * 128);
  float* Pcnt = alloc(64);
  int* deg    = (int*)alloc(N);
  int* fil    = (int*)alloc(N);
  float* es3  = alloc(N);
  float* ed3  = alloc(N);
  size_t zend = off;
  int* rowptr = (int*)alloc(N + 1);
  int* bsum   = (int*)alloc(512);
  int* boff   = (int*)alloc(512);
  int* csr    = (int*)alloc(Etot);
  (void)ws_size; (void)n_in; (void)out_size;

  (void)hipMemsetAsync(Ps, 0, (size_t)((base + zend) - Ps) * sizeof(float), stream);

  WPtrs wp;
  wp.w[0]=Wi1; wp.w[1]=Wi2; wp.w[2]=Wg[0]; wp.w[3]=Wg[1]; wp.w[4]=Wg[2]; wp.w[5]=Wg[3]; wp.w[6]=We1; wp.w[7]=We2;
  k_wcast<<<dim3(8, 8), 256, 0, stream>>>(wp, Wh);

  const int g2 = (N + 31) / 32;
  const int gtiles = 2 * g2;
  // input_proj: Ah = half(relu(x@Wi1^T+bi1)@Wi2^T+bi2)
  k_gemm2<float, 0><<<g2, 256, 0, stream>>>(x, Wh + 0*16384, Wh + 1*16384, bi1, bi2,
                                            nullptr, Ah, nullptr, nullptr, nullptr, nullptr, nullptr, N);

  const int nb = (N + 255) / 256;
  k_deg  <<<(Etot + 255) / 256, 256, 0, stream>>>(ei, deg, E, N);
  k_scan1<<<nb, 256, 0, stream>>>(deg, bsum, N);
  k_scan2<<<1, 256, 0, stream>>>(bsum, boff, nb);
  k_scan3<<<nb, 256, 0, stream>>>(deg, boff, rowptr, N);
  k_fill <<<(Etot + 255) / 256, 256, 0, stream>>>(ei, rowptr, fil, csr, E, N);

  for (int l = 0; l < 4; l++){
    if (l < 3){
      k_gat_gemm<1><<<gtiles, 256, 0, stream>>>(Ah, Wh + (size_t)(2+l)*16384, As[l], Ad[l],
                                                es, ed, Xh, N);
      k_aggregate<8,16><<<(N + 3) / 4, 256, 0, stream>>>(Xh, es, ed, rowptr, csr, bg[l],
                                                         l > 0 ? Ah : nullptr, Ah, N);
    } else {
      k_gat_gemm<2><<<gtiles, 256, 0, stream>>>(Ah, Wh + 5*16384, As[3], Ad[3],
                                                es3, ed3, Xh, N);
      k_aggregate<1,128><<<(N + 3) / 4, 256, 0, stream>>>(Xh, es3, ed3, rowptr, csr, bg[3],
                                                          Ah, Ah, N);
    }
  }

  // enh = Ah + (relu(Ah@We1^T+be1)@We2^T + be2) -> fused pooling atomics only
  k_gemm2<__half, 1><<<g2, 256, 0, stream>>>(Ah, Wh + 6*16384, Wh + 7*16384, be1, be2,
                                             Ah, nullptr, batch, Ps, Pss, Pmx, Pcnt, N);

  k_poolcls<<<64, 128, 0, stream>>>(Ps, Pss, Pmx, Pcnt, Wc1, bc1, Wc2, bc2, Wc3, bc3, outp);
}